// Round 1
// baseline (69.746 us; speedup 1.0000x reference)
//
#include <hip/hip_runtime.h>

#define B 128
#define N 512
#define D 256
#define S 8

// ---------------------------------------------------------------------------
// k0: key_attn[b,n] = sum_s att_stack[b,n,s]*sp[b,s];
//     new_att_stack = att_stack*(1-sp); new_stack_ptr = shift-down(sp)
// ---------------------------------------------------------------------------
__global__ void k0_stack(const float* __restrict__ att_stack,
                         const float* __restrict__ stack_ptr,
                         float* __restrict__ out_att,
                         float* __restrict__ out_sp,
                         float* __restrict__ ka) {
    const int b = blockIdx.x;
    const int tid = threadIdx.x;
    __shared__ float sp[S];
    __shared__ float omsp[S];
    if (tid < S) {
        float v = stack_ptr[b * S + tid];
        sp[tid] = v;
        omsp[tid] = 1.0f - v;
    }
    __syncthreads();
    for (int n = tid; n < N; n += blockDim.x) {
        const float4* src = reinterpret_cast<const float4*>(att_stack + ((size_t)(b * N + n)) * S);
        float4 a0 = src[0], a1 = src[1];
        float kacc = a0.x * sp[0] + a0.y * sp[1] + a0.z * sp[2] + a0.w * sp[3]
                   + a1.x * sp[4] + a1.y * sp[5] + a1.z * sp[6] + a1.w * sp[7];
        ka[b * N + n] = kacc;
        float4 o0 = make_float4(a0.x * omsp[0], a0.y * omsp[1], a0.z * omsp[2], a0.w * omsp[3]);
        float4 o1 = make_float4(a1.x * omsp[4], a1.y * omsp[5], a1.z * omsp[6], a1.w * omsp[7]);
        float4* dst = reinterpret_cast<float4*>(out_att + ((size_t)(b * N + n)) * S);
        dst[0] = o0;
        dst[1] = o1;
    }
    if (tid < S) {
        float v = (tid < S - 1) ? sp[tid + 1] : 0.0f;
        if (tid == 0) v += sp[0];
        out_sp[b * S + tid] = v;
    }
}

// ---------------------------------------------------------------------------
// kA: edge_matrix[b,j] += sum_{i in chunk} edge[b,i,j] * ka[b,i]
// grid (N/64 chunks, B), block 128 threads, each thread owns 4 consecutive j
// ---------------------------------------------------------------------------
__global__ void kA_edge(const float* __restrict__ edge,
                        const float* __restrict__ ka,
                        float* __restrict__ em) {
    const int b = blockIdx.y;
    const int i0 = blockIdx.x * 64;
    const int tid = threadIdx.x;
    __shared__ float kal[64];
    if (tid < 64) kal[tid] = ka[b * N + i0 + tid];
    __syncthreads();
    float4 acc = make_float4(0.f, 0.f, 0.f, 0.f);
    const float4* base = reinterpret_cast<const float4*>(edge + ((size_t)b * N + i0) * N) + tid;
    #pragma unroll 8
    for (int i = 0; i < 64; ++i) {
        float4 v = base[(size_t)i * (N / 4)];
        float k = kal[i];
        acc.x += k * v.x; acc.y += k * v.y; acc.z += k * v.z; acc.w += k * v.w;
    }
    float* dst = em + b * N + tid * 4;
    unsafeAtomicAdd(dst + 0, acc.x);
    unsafeAtomicAdd(dst + 1, acc.y);
    unsafeAtomicAdd(dst + 2, acc.z);
    unsafeAtomicAdd(dst + 3, acc.w);
}

// ---------------------------------------------------------------------------
// kB: key_feat[b,d] += sum_{n in chunk} node[b,n,d] * ka[b,n]
// grid (N/64 chunks, B), block 64 threads, each thread owns 4 consecutive d
// ---------------------------------------------------------------------------
__global__ void kB_keyfeat(const float* __restrict__ node,
                           const float* __restrict__ ka,
                           float* __restrict__ kf) {
    const int b = blockIdx.y;
    const int n0 = blockIdx.x * 64;
    const int tid = threadIdx.x;
    __shared__ float kal[64];
    kal[tid] = ka[b * N + n0 + tid];
    __syncthreads();
    float4 acc = make_float4(0.f, 0.f, 0.f, 0.f);
    const float4* base = reinterpret_cast<const float4*>(node + ((size_t)b * N + n0) * D) + tid;
    #pragma unroll 8
    for (int i = 0; i < 64; ++i) {
        float4 v = base[(size_t)i * (D / 4)];
        float k = kal[i];
        acc.x += k * v.x; acc.y += k * v.y; acc.z += k * v.z; acc.w += k * v.w;
    }
    float* dst = kf + b * D + tid * 4;
    unsafeAtomicAdd(dst + 0, acc.x);
    unsafeAtomicAdd(dst + 1, acc.y);
    unsafeAtomicAdd(dst + 2, acc.z);
    unsafeAtomicAdd(dst + 3, acc.w);
}

// ---------------------------------------------------------------------------
// kC: q[b,d] = bias[d] + sum_k W[d,k] * kf[b,k]
// grid B, block D threads (one output each); kf staged in LDS
// ---------------------------------------------------------------------------
__global__ void kC_q(const float* __restrict__ Wm,
                     const float* __restrict__ bias,
                     const float* __restrict__ kf,
                     float* __restrict__ q) {
    const int b = blockIdx.x;
    const int d = threadIdx.x;
    __shared__ float kfl[D];
    kfl[d] = kf[b * D + d];
    __syncthreads();
    float acc = bias[d];
    const float4* wrow = reinterpret_cast<const float4*>(Wm + (size_t)d * D);
    const float4* kf4 = reinterpret_cast<const float4*>(kfl);
    #pragma unroll 8
    for (int k = 0; k < D / 4; ++k) {
        float4 w = wrow[k];
        float4 f = kf4[k];
        acc += w.x * f.x + w.y * f.y + w.z * f.z + w.w * f.w;
    }
    q[b * D + d] = acc;
}

// ---------------------------------------------------------------------------
// kD: out_vm[b,n] = vm[b,n] + em[b,n] * dot(node[b,n,:], q[b,:])
// one wave (64 lanes x float4 = 256 floats) per row; 32 rows per block
// ---------------------------------------------------------------------------
__global__ void kD_logits(const float* __restrict__ node,
                          const float* __restrict__ em,
                          const float* __restrict__ q,
                          const float* __restrict__ vm,
                          float* __restrict__ out_vm) {
    const int row0 = blockIdx.x * 32;      // 32 rows per block, all in same b (512 % 32 == 0)
    const int b = row0 / N;
    const int tid = threadIdx.x;
    const int wave = tid >> 6;
    const int lane = tid & 63;
    __shared__ float ql[D];
    if (tid < D) ql[tid] = q[b * D + tid];
    __syncthreads();
    const float4 q4 = reinterpret_cast<const float4*>(ql)[lane];
    #pragma unroll
    for (int r = 0; r < 8; ++r) {
        const int row = row0 + wave * 8 + r;
        const float4 v = reinterpret_cast<const float4*>(node + (size_t)row * D)[lane];
        float s = v.x * q4.x + v.y * q4.y + v.z * q4.z + v.w * q4.w;
        #pragma unroll
        for (int off = 32; off; off >>= 1) s += __shfl_xor(s, off);
        if (lane == 0) {
            out_vm[row] = vm[row] + em[row] * s;
        }
    }
}

extern "C" void kernel_launch(void* const* d_in, const int* in_sizes, int n_in,
                              void* d_out, int out_size, void* d_ws, size_t ws_size,
                              hipStream_t stream) {
    const float* node = (const float*)d_in[0];
    // d_in[1] = query : unused by the reference computation
    const float* edge = (const float*)d_in[2];
    const float* att  = (const float*)d_in[3];
    const float* sp   = (const float*)d_in[4];
    const float* vm   = (const float*)d_in[5];
    const float* Wm   = (const float*)d_in[6];
    const float* bias = (const float*)d_in[7];

    float* out_att = (float*)d_out;                    // B*N*S
    float* out_sp  = out_att + (size_t)B * N * S;      // B*S
    float* out_vm  = out_sp + (size_t)B * S;           // B*N

    float* ws = (float*)d_ws;
    float* ka = ws;                          // B*N
    float* kf = ws + (size_t)B * N;          // B*D (accumulated -> zero)
    float* em = kf + (size_t)B * D;          // B*N (accumulated -> zero)
    float* q  = em + (size_t)B * N;          // B*D

    // zero the two atomically-accumulated regions (contiguous: kf then em)
    hipMemsetAsync(kf, 0, (size_t)(B * D + B * N) * sizeof(float), stream);

    k0_stack<<<B, 256, 0, stream>>>(att, sp, out_att, out_sp, ka);
    kA_edge<<<dim3(N / 64, B), 128, 0, stream>>>(edge, ka, em);
    kB_keyfeat<<<dim3(N / 64, B), 64, 0, stream>>>(node, ka, kf);
    kC_q<<<B, D, 0, stream>>>(Wm, bias, kf, q);
    kD_logits<<<(B * N) / 32, 256, 0, stream>>>(node, em, q, vm, out_vm);
}

// Round 2
// 63.737 us; speedup vs baseline: 1.0943x; 1.0943x over previous
//
#include <hip/hip_runtime.h>

#define B 128
#define N 512
#define D 256
#define S 8

// ---------------------------------------------------------------------------
// K1 (fused): grid (16, B), block 128.
//   role = blockIdx.x in [0,8): edge chunk  -> em[b,:] += sum_i edge[b,i,:]*ka[b,i]
//   role in [8,16):            node chunk  -> kf[b,:] += sum_n node[b,n,:]*ka[b,n]
//                                             + write out_att chunk (+ out_sp once)
// Each block recomputes its own 64-entry ka chunk from att_stack & stack_ptr,
// so there is no dependency on a predecessor kernel and both big streams
// (edge 128 MiB, node 64 MiB) are in flight simultaneously.
// ---------------------------------------------------------------------------
__global__ __launch_bounds__(128) void k1_fused(
    const float* __restrict__ node, const float* __restrict__ edge,
    const float* __restrict__ att, const float* __restrict__ spi,
    float* __restrict__ out_att, float* __restrict__ out_sp,
    float* __restrict__ kf, float* __restrict__ em) {
    const int b = blockIdx.y;
    const int role = blockIdx.x;
    const int tid = threadIdx.x;
    __shared__ float sps[S];
    __shared__ float kal[64];
    __shared__ float4 red[64];
    if (tid < S) sps[tid] = spi[b * S + tid];
    __syncthreads();

    if (role < 8) {
        // ---- edge reduction chunk ----
        const int i0 = role * 64;
        if (tid < 64) {
            const float4* a = reinterpret_cast<const float4*>(att + ((size_t)(b * N + i0 + tid)) * S);
            float4 a0 = a[0], a1 = a[1];
            kal[tid] = a0.x * sps[0] + a0.y * sps[1] + a0.z * sps[2] + a0.w * sps[3]
                     + a1.x * sps[4] + a1.y * sps[5] + a1.z * sps[6] + a1.w * sps[7];
        }
        __syncthreads();
        float4 acc = make_float4(0.f, 0.f, 0.f, 0.f);
        const float4* base = reinterpret_cast<const float4*>(edge + ((size_t)(b * N + i0)) * N) + tid;
        #pragma unroll 8
        for (int i = 0; i < 64; ++i) {
            float4 v = base[(size_t)i * (N / 4)];
            float k = kal[i];
            acc.x += k * v.x; acc.y += k * v.y; acc.z += k * v.z; acc.w += k * v.w;
        }
        float* dst = em + b * N + tid * 4;
        unsafeAtomicAdd(dst + 0, acc.x);
        unsafeAtomicAdd(dst + 1, acc.y);
        unsafeAtomicAdd(dst + 2, acc.z);
        unsafeAtomicAdd(dst + 3, acc.w);
    } else {
        // ---- node reduction chunk (+ stack outputs) ----
        const int n0 = (role - 8) * 64;
        if (tid < 64) {
            const float4* a = reinterpret_cast<const float4*>(att + ((size_t)(b * N + n0 + tid)) * S);
            float4 a0 = a[0], a1 = a[1];
            kal[tid] = a0.x * sps[0] + a0.y * sps[1] + a0.z * sps[2] + a0.w * sps[3]
                     + a1.x * sps[4] + a1.y * sps[5] + a1.z * sps[6] + a1.w * sps[7];
            float4 o0 = make_float4(a0.x * (1.f - sps[0]), a0.y * (1.f - sps[1]),
                                    a0.z * (1.f - sps[2]), a0.w * (1.f - sps[3]));
            float4 o1 = make_float4(a1.x * (1.f - sps[4]), a1.y * (1.f - sps[5]),
                                    a1.z * (1.f - sps[6]), a1.w * (1.f - sps[7]));
            float4* oa = reinterpret_cast<float4*>(out_att + ((size_t)(b * N + n0 + tid)) * S);
            oa[0] = o0;
            oa[1] = o1;
        }
        if (role == 8 && tid < S) {
            float v = (tid < S - 1) ? sps[tid + 1] : 0.0f;
            if (tid == 0) v += sps[0];
            out_sp[b * S + tid] = v;
        }
        __syncthreads();
        const int col = tid & 63;           // float4 column of D
        const int r0 = (tid >> 6) * 32;     // row half
        float4 acc = make_float4(0.f, 0.f, 0.f, 0.f);
        const float4* base = reinterpret_cast<const float4*>(node + ((size_t)(b * N + n0)) * D) + col;
        #pragma unroll 8
        for (int i = 0; i < 32; ++i) {
            float4 v = base[(size_t)(r0 + i) * (D / 4)];
            float k = kal[r0 + i];
            acc.x += k * v.x; acc.y += k * v.y; acc.z += k * v.z; acc.w += k * v.w;
        }
        if (tid >= 64) red[col] = acc;
        __syncthreads();
        if (tid < 64) {
            float4 o = red[col];
            acc.x += o.x; acc.y += o.y; acc.z += o.z; acc.w += o.w;
            float* dst = kf + b * D + col * 4;
            unsafeAtomicAdd(dst + 0, acc.x);
            unsafeAtomicAdd(dst + 1, acc.y);
            unsafeAtomicAdd(dst + 2, acc.z);
            unsafeAtomicAdd(dst + 3, acc.w);
        }
    }
}

// ---------------------------------------------------------------------------
// K2: q[b,d] = bias[d] + sum_k W[d,k] * kf[b,k]   (grid B, block D)
// ---------------------------------------------------------------------------
__global__ void kC_q(const float* __restrict__ Wm,
                     const float* __restrict__ bias,
                     const float* __restrict__ kf,
                     float* __restrict__ q) {
    const int b = blockIdx.x;
    const int d = threadIdx.x;
    __shared__ float kfl[D];
    kfl[d] = kf[b * D + d];
    __syncthreads();
    float acc = bias[d];
    const float4* wrow = reinterpret_cast<const float4*>(Wm + (size_t)d * D);
    const float4* kf4 = reinterpret_cast<const float4*>(kfl);
    #pragma unroll 8
    for (int k = 0; k < D / 4; ++k) {
        float4 w = wrow[k];
        float4 f = kf4[k];
        acc += w.x * f.x + w.y * f.y + w.z * f.z + w.w * f.w;
    }
    q[b * D + d] = acc;
}

// ---------------------------------------------------------------------------
// K3: out_vm[b,n] = vm[b,n] + em[b,n] * dot(node[b,n,:], q[b,:])
// one wave (64 lanes x float4 = 256 floats) per row; 32 rows per block
// ---------------------------------------------------------------------------
__global__ void kD_logits(const float* __restrict__ node,
                          const float* __restrict__ em,
                          const float* __restrict__ q,
                          const float* __restrict__ vm,
                          float* __restrict__ out_vm) {
    const int row0 = blockIdx.x * 32;
    const int b = row0 / N;
    const int tid = threadIdx.x;
    const int wave = tid >> 6;
    const int lane = tid & 63;
    __shared__ float ql[D];
    if (tid < D) ql[tid] = q[b * D + tid];
    __syncthreads();
    const float4 q4 = reinterpret_cast<const float4*>(ql)[lane];
    #pragma unroll
    for (int r = 0; r < 8; ++r) {
        const int row = row0 + wave * 8 + r;
        const float4 v = reinterpret_cast<const float4*>(node + (size_t)row * D)[lane];
        float s = v.x * q4.x + v.y * q4.y + v.z * q4.z + v.w * q4.w;
        #pragma unroll
        for (int off = 32; off; off >>= 1) s += __shfl_xor(s, off);
        if (lane == 0) {
            out_vm[row] = vm[row] + em[row] * s;
        }
    }
}

extern "C" void kernel_launch(void* const* d_in, const int* in_sizes, int n_in,
                              void* d_out, int out_size, void* d_ws, size_t ws_size,
                              hipStream_t stream) {
    const float* node = (const float*)d_in[0];
    // d_in[1] = query : unused by the reference computation
    const float* edge = (const float*)d_in[2];
    const float* att  = (const float*)d_in[3];
    const float* sp   = (const float*)d_in[4];
    const float* vm   = (const float*)d_in[5];
    const float* Wm   = (const float*)d_in[6];
    const float* bias = (const float*)d_in[7];

    float* out_att = (float*)d_out;                    // B*N*S
    float* out_sp  = out_att + (size_t)B * N * S;      // B*S
    float* out_vm  = out_sp + (size_t)B * S;           // B*N

    float* ws = (float*)d_ws;
    float* kf = ws;                          // B*D (atomic-accumulated -> zero)
    float* em = kf + (size_t)B * D;          // B*N (atomic-accumulated -> zero)
    float* q  = em + (size_t)B * N;          // B*D

    hipMemsetAsync(kf, 0, (size_t)(B * D + B * N) * sizeof(float), stream);

    k1_fused<<<dim3(16, B), 128, 0, stream>>>(node, edge, att, sp,
                                              out_att, out_sp, kf, em);
    kC_q<<<B, D, 0, stream>>>(Wm, bias, kf, q);
    kD_logits<<<(B * N) / 32, 256, 0, stream>>>(node, em, q, vm, out_vm);
}

// Round 3
// 63.236 us; speedup vs baseline: 1.1029x; 1.0079x over previous
//
#include <hip/hip_runtime.h>

#define B 128
#define N 512
#define D 256
#define S 8

// ---------------------------------------------------------------------------
// K1 (fused): grid (16, B), block 128.
//   role in [0,8):  edge chunk -> em[b,:] += sum_i edge[b,i,:]*ka[b,i]
//   role in [8,16): node chunk -> kf[b,:] += sum_n node[b,n,:]*ka[b,n]
//                                 + out_att chunk (+ out_sp once)
// Explicit 16-deep load batching: v[16] filled before any FMA so the
// compiler keeps 16 float4 loads in flight per thread (fixes VGPR=28
// latency-bound stall seen in R2 profile).
// ---------------------------------------------------------------------------
__global__ __launch_bounds__(128) void k1_fused(
    const float* __restrict__ node, const float* __restrict__ edge,
    const float* __restrict__ att, const float* __restrict__ spi,
    float* __restrict__ out_att, float* __restrict__ out_sp,
    float* __restrict__ kf, float* __restrict__ em) {
    const int b = blockIdx.y;
    const int role = blockIdx.x;
    const int tid = threadIdx.x;
    __shared__ float sps[S];
    __shared__ float kal[64];
    __shared__ float4 red[64];
    if (tid < S) sps[tid] = spi[b * S + tid];
    __syncthreads();

    if (role < 8) {
        // ---- edge reduction chunk: 64 rows x 512 cols ----
        const int i0 = role * 64;
        if (tid < 64) {
            const float4* a = reinterpret_cast<const float4*>(att + ((size_t)(b * N + i0 + tid)) * S);
            float4 a0 = a[0], a1 = a[1];
            kal[tid] = a0.x * sps[0] + a0.y * sps[1] + a0.z * sps[2] + a0.w * sps[3]
                     + a1.x * sps[4] + a1.y * sps[5] + a1.z * sps[6] + a1.w * sps[7];
        }
        __syncthreads();
        float4 acc = make_float4(0.f, 0.f, 0.f, 0.f);
        const float4* base = reinterpret_cast<const float4*>(edge + ((size_t)(b * N + i0)) * N) + tid;
        float4 v[16];
        for (int ii = 0; ii < 64; ii += 16) {
            #pragma unroll
            for (int u = 0; u < 16; ++u) v[u] = base[(size_t)(ii + u) * (N / 4)];
            #pragma unroll
            for (int u = 0; u < 16; ++u) {
                float k = kal[ii + u];
                acc.x += k * v[u].x; acc.y += k * v[u].y;
                acc.z += k * v[u].z; acc.w += k * v[u].w;
            }
        }
        float* dst = em + b * N + tid * 4;
        unsafeAtomicAdd(dst + 0, acc.x);
        unsafeAtomicAdd(dst + 1, acc.y);
        unsafeAtomicAdd(dst + 2, acc.z);
        unsafeAtomicAdd(dst + 3, acc.w);
    } else {
        // ---- node reduction chunk: 64 rows x 256 cols (+ stack outputs) ----
        const int n0 = (role - 8) * 64;
        if (tid < 64) {
            const float4* a = reinterpret_cast<const float4*>(att + ((size_t)(b * N + n0 + tid)) * S);
            float4 a0 = a[0], a1 = a[1];
            kal[tid] = a0.x * sps[0] + a0.y * sps[1] + a0.z * sps[2] + a0.w * sps[3]
                     + a1.x * sps[4] + a1.y * sps[5] + a1.z * sps[6] + a1.w * sps[7];
            float4 o0 = make_float4(a0.x * (1.f - sps[0]), a0.y * (1.f - sps[1]),
                                    a0.z * (1.f - sps[2]), a0.w * (1.f - sps[3]));
            float4 o1 = make_float4(a1.x * (1.f - sps[4]), a1.y * (1.f - sps[5]),
                                    a1.z * (1.f - sps[6]), a1.w * (1.f - sps[7]));
            float4* oa = reinterpret_cast<float4*>(out_att + ((size_t)(b * N + n0 + tid)) * S);
            oa[0] = o0;
            oa[1] = o1;
        }
        if (role == 8 && tid < S) {
            float v = (tid < S - 1) ? sps[tid + 1] : 0.0f;
            if (tid == 0) v += sps[0];
            out_sp[b * S + tid] = v;
        }
        __syncthreads();
        const int col = tid & 63;           // float4 column of D
        const int r0 = (tid >> 6) * 32;     // row half
        float4 acc = make_float4(0.f, 0.f, 0.f, 0.f);
        const float4* base = reinterpret_cast<const float4*>(node + ((size_t)(b * N + n0)) * D) + col;
        float4 v[16];
        for (int ii = 0; ii < 32; ii += 16) {
            #pragma unroll
            for (int u = 0; u < 16; ++u) v[u] = base[(size_t)(r0 + ii + u) * (D / 4)];
            #pragma unroll
            for (int u = 0; u < 16; ++u) {
                float k = kal[r0 + ii + u];
                acc.x += k * v[u].x; acc.y += k * v[u].y;
                acc.z += k * v[u].z; acc.w += k * v[u].w;
            }
        }
        if (tid >= 64) red[col] = acc;
        __syncthreads();
        if (tid < 64) {
            float4 o = red[col];
            acc.x += o.x; acc.y += o.y; acc.z += o.z; acc.w += o.w;
            float* dst = kf + b * D + col * 4;
            unsafeAtomicAdd(dst + 0, acc.x);
            unsafeAtomicAdd(dst + 1, acc.y);
            unsafeAtomicAdd(dst + 2, acc.z);
            unsafeAtomicAdd(dst + 3, acc.w);
        }
    }
}

// ---------------------------------------------------------------------------
// K2: q[b,d] = bias[d] + sum_k W[d,k] * kf[b,k]   (grid B, block D)
// ---------------------------------------------------------------------------
__global__ void kC_q(const float* __restrict__ Wm,
                     const float* __restrict__ bias,
                     const float* __restrict__ kf,
                     float* __restrict__ q) {
    const int b = blockIdx.x;
    const int d = threadIdx.x;
    __shared__ float kfl[D];
    kfl[d] = kf[b * D + d];
    __syncthreads();
    float acc = bias[d];
    const float4* wrow = reinterpret_cast<const float4*>(Wm + (size_t)d * D);
    const float4* kf4 = reinterpret_cast<const float4*>(kfl);
    float4 w[8];
    for (int k0 = 0; k0 < D / 4; k0 += 8) {
        #pragma unroll
        for (int u = 0; u < 8; ++u) w[u] = wrow[k0 + u];
        #pragma unroll
        for (int u = 0; u < 8; ++u) {
            float4 f = kf4[k0 + u];
            acc += w[u].x * f.x + w[u].y * f.y + w[u].z * f.z + w[u].w * f.w;
        }
    }
    q[b * D + d] = acc;
}

// ---------------------------------------------------------------------------
// K3: out_vm[b,n] = vm[b,n] + em[b,n] * dot(node[b,n,:], q[b,:])
// one wave (64 lanes x float4 = 256 floats) per row; 32 rows per block.
// All 8 row-loads issued before the first reduce; epilogue vectorized
// across lanes 0..7.
// ---------------------------------------------------------------------------
__global__ void kD_logits(const float* __restrict__ node,
                          const float* __restrict__ em,
                          const float* __restrict__ q,
                          const float* __restrict__ vm,
                          float* __restrict__ out_vm) {
    const int row0 = blockIdx.x * 32;
    const int b = row0 / N;
    const int tid = threadIdx.x;
    const int wave = tid >> 6;
    const int lane = tid & 63;
    __shared__ float ql[D];
    if (tid < D) ql[tid] = q[b * D + tid];
    __syncthreads();
    const float4 q4 = reinterpret_cast<const float4*>(ql)[lane];
    const int wr0 = row0 + wave * 8;
    float emv = 0.f, vmv = 0.f;
    if (lane < 8) {
        emv = em[wr0 + lane];
        vmv = vm[wr0 + lane];
    }
    float4 v[8];
    #pragma unroll
    for (int r = 0; r < 8; ++r)
        v[r] = reinterpret_cast<const float4*>(node + (size_t)(wr0 + r) * D)[lane];
    float myS = 0.f;
    #pragma unroll
    for (int r = 0; r < 8; ++r) {
        float s = v[r].x * q4.x + v[r].y * q4.y + v[r].z * q4.z + v[r].w * q4.w;
        #pragma unroll
        for (int off = 32; off; off >>= 1) s += __shfl_xor(s, off);
        if (lane == r) myS = s;
    }
    if (lane < 8) {
        out_vm[wr0 + lane] = vmv + emv * myS;
    }
}

extern "C" void kernel_launch(void* const* d_in, const int* in_sizes, int n_in,
                              void* d_out, int out_size, void* d_ws, size_t ws_size,
                              hipStream_t stream) {
    const float* node = (const float*)d_in[0];
    // d_in[1] = query : unused by the reference computation
    const float* edge = (const float*)d_in[2];
    const float* att  = (const float*)d_in[3];
    const float* sp   = (const float*)d_in[4];
    const float* vm   = (const float*)d_in[5];
    const float* Wm   = (const float*)d_in[6];
    const float* bias = (const float*)d_in[7];

    float* out_att = (float*)d_out;                    // B*N*S
    float* out_sp  = out_att + (size_t)B * N * S;      // B*S
    float* out_vm  = out_sp + (size_t)B * S;           // B*N

    float* ws = (float*)d_ws;
    float* kf = ws;                          // B*D (atomic-accumulated -> zero)
    float* em = kf + (size_t)B * D;          // B*N (atomic-accumulated -> zero)
    float* q  = em + (size_t)B * N;          // B*D

    hipMemsetAsync(kf, 0, (size_t)(B * D + B * N) * sizeof(float), stream);

    k1_fused<<<dim3(16, B), 128, 0, stream>>>(node, edge, att, sp,
                                              out_att, out_sp, kf, em);
    kC_q<<<B, D, 0, stream>>>(Wm, bias, kf, q);
    kD_logits<<<(B * N) / 32, 256, 0, stream>>>(node, em, q, vm, out_vm);
}